// Round 4
// baseline (647.466 us; speedup 1.0000x reference)
//
#include <hip/hip_runtime.h>
#include <hip/hip_bf16.h>

// Problem constants: IN=512, OUT=512, H=8, B=4, FH=64
#define KDIM 512
#define ODIM 512
#define NB 4
#define NH 8
#define FH 64
#define BFH 256   // B*FH
#define HB 32     // H*B
#define NCAT 896  // 256 bases | 32 comb | 512 res | 96 pad
#define COL_W 256 // weight col offset in Cb
#define COL_R 288 // residual col offset in Cb
#define LN_EPS 1e-5f
#define SCAN_T 1024

typedef __attribute__((ext_vector_type(8))) short short8;
typedef __attribute__((ext_vector_type(4))) float floatx4;

__device__ __forceinline__ float b2f(unsigned short u) {
    union { unsigned int i; float f; } v; v.i = ((unsigned int)u) << 16; return v.f;
}
__device__ __forceinline__ unsigned short f2b(float f) {
    __hip_bfloat16 h = __float2bfloat16(f);
    return *(unsigned short*)&h;
}
__device__ __forceinline__ void async16(const void* g, void* l) {
    __builtin_amdgcn_global_load_lds(
        (__attribute__((address_space(1))) unsigned int*)(g),
        (__attribute__((address_space(3))) unsigned int*)(l),
        16, 0, 0);
}

// ---------------------------------------------------------------------------
__global__ void deg_kernel(const int* __restrict__ dst, int* __restrict__ deg, int E) {
    int i = blockIdx.x * blockDim.x + threadIdx.x;
    if (i < E) atomicAdd(&deg[dst[i]], 1);
}

// single-block exclusive scan of deg -> offsets[0..N] + woff copy + dinv
__global__ __launch_bounds__(SCAN_T) void scan_kernel(
        const int* __restrict__ deg, int* __restrict__ offsets,
        int* __restrict__ woff, float* __restrict__ dinv, int N) {
    __shared__ int sm[SCAN_T];
    int t = threadIdx.x;
    int C = (N + SCAN_T - 1) / SCAN_T;
    int start = t * C;
    int end = min(start + C, N);
    int local = 0;
    for (int i = start; i < end; i++) local += deg[i];
    sm[t] = local;
    __syncthreads();
    for (int o = 1; o < SCAN_T; o <<= 1) {
        int v = (t >= o) ? sm[t - o] : 0;
        __syncthreads();
        sm[t] += v;
        __syncthreads();
    }
    int running = sm[t] - local;
    for (int i = start; i < end; i++) {
        int d = deg[i];
        offsets[i] = running;
        woff[i] = running;
        dinv[i] = rsqrtf((float)d + 1.0f);
        running += d;
    }
    if (end == N && start < N) offsets[N] = running;
}

__global__ void fill_kernel(const int* __restrict__ src, const int* __restrict__ dst,
                            int* __restrict__ woff, int* __restrict__ ebuf, int E) {
    int i = blockIdx.x * blockDim.x + threadIdx.x;
    if (i < E) {
        int pos = atomicAdd(&woff[dst[i]], 1);
        ebuf[pos] = src[i];
    }
}

// ---------------------------------------------------------------------------
// Fused: x fp32->bf16  AND  WcatT [896][512] bf16 staging + bias_cat.
__global__ __launch_bounds__(256) void prep_kernel(
        const float* __restrict__ x, unsigned short* __restrict__ xb, long total4,
        int nCvtBlocks,
        const float* __restrict__ Wb, const float* __restrict__ Wc,
        const float* __restrict__ Wr, const float* __restrict__ bcomb,
        const float* __restrict__ bres,
        unsigned short* __restrict__ wT, float* __restrict__ bias_cat) {
    int blk = blockIdx.x;
    if (blk < nCvtBlocks) {
        long i = (long)blk * 256 + threadIdx.x;
        if (i >= total4) return;
        float4 v = ((const float4*)x)[i];
        ushort4 u;
        u.x = f2b(v.x); u.y = f2b(v.y); u.z = f2b(v.z); u.w = f2b(v.w);
        ((ushort4*)xb)[i] = u;
    } else {
        int idx = (blk - nCvtBlocks) * 256 + threadIdx.x;
        if (idx >= NCAT * KDIM) return;
        int c = idx >> 9, k = idx & (KDIM - 1);
        float v;
        if (c < BFH)                   v = Wb[(size_t)k * BFH + c];
        else if (c < COL_R)            v = Wc[(size_t)k * HB + (c - COL_W)];
        else if (c < COL_R + ODIM)     v = Wr[(size_t)k * ODIM + (c - COL_R)];
        else                           v = 0.0f;
        wT[(size_t)c * KDIM + k] = f2b(v);
        if (k == 0) {
            float bv = 0.0f;
            if (c >= COL_W && c < COL_R)            bv = bcomb[c - COL_W];
            else if (c >= COL_R && c < COL_R + ODIM) bv = bres[c - COL_R];
            bias_cat[c] = bv;
        }
    }
}

// ---------------------------------------------------------------------------
// bf16 MFMA GEMM: Cb[N,896] = xb[N,512] @ wT^T + bias_cat, output bf16.
// m97 recipe: global_load_lds dwordx4 staging, no LDS pad, 2-barrier K-loop.
// Epilogue: LDS transpose -> full-cacheline 256B contiguous stores.
#define BM 128
#define BN 128
#define BK 32
#define SLD 136   // epilogue stage row stride (ushorts); 272B rows, 16B-aligned

__global__ __launch_bounds__(256) void mfma_gemm_kernel(
        const unsigned short* __restrict__ xb,   // [N,512] bf16 bits
        const unsigned short* __restrict__ wT,   // [896,512] bf16 bits
        const float* __restrict__ bias_cat,      // [896]
        unsigned short* __restrict__ Cb,         // [N,896] bf16 bits
        int N) {
    __shared__ short lds[8192];                  // As 4096 | Bs 4096 shorts
    short* As = lds;
    short* Bs = lds + 4096;
    int t = threadIdx.x;
    int l = t & 63, w = t >> 6;
    int wr = w >> 1, wc = w & 1;
    int quad = l >> 4, m = l & 15;
    int row0 = blockIdx.y * BM;
    int col0 = blockIdx.x * BN;

    floatx4 acc[4][4];
    floatx4 zero4 = {0.f, 0.f, 0.f, 0.f};
    #pragma unroll
    for (int i = 0; i < 4; i++)
        #pragma unroll
        for (int j = 0; j < 4; j++) acc[i][j] = zero4;

    // staging: issue s covers tile rows s*64 + w*16 + l/4, k = (l%4)*8 .. +8
    int ar0 = row0 + (w << 4) + (l >> 2);
    int ar1 = ar0 + 64;
    int brow = col0 + (w << 4) + (l >> 2);
    int kk = (l & 3) * 8;
    const unsigned short* agp0 = xb + (size_t)min(ar0, N - 1) * KDIM + kk;
    const unsigned short* agp1 = xb + (size_t)min(ar1, N - 1) * KDIM + kk;
    const unsigned short* bgp0 = wT + (size_t)brow * KDIM + kk;
    const unsigned short* bgp1 = bgp0 + (size_t)64 * KDIM;
    short* al0 = As + w * 512;          // (s*256 + w*64)*8 shorts
    short* al1 = As + 2048 + w * 512;
    short* bl0 = Bs + w * 512;
    short* bl1 = Bs + 2048 + w * 512;

    for (int k0 = 0; k0 < KDIM; k0 += BK) {
        __syncthreads();                 // previous tile fully consumed
        async16(agp0 + k0, al0);
        async16(agp1 + k0, al1);
        async16(bgp0 + k0, bl0);
        async16(bgp1 + k0, bl1);
        __syncthreads();                 // vmcnt(0) drained before barrier

        short8 a[4], b[4];
        #pragma unroll
        for (int i = 0; i < 4; i++)
            a[i] = *(const short8*)(As + (wr * 64 + i * 16 + m) * BK + quad * 8);
        #pragma unroll
        for (int j = 0; j < 4; j++)
            b[j] = *(const short8*)(Bs + (wc * 64 + j * 16 + m) * BK + quad * 8);
        #pragma unroll
        for (int i = 0; i < 4; i++)
            #pragma unroll
            for (int j = 0; j < 4; j++)
                acc[i][j] = __builtin_amdgcn_mfma_f32_16x16x32_bf16(
                    a[i], b[j], acc[i][j], 0, 0, 0);
    }

    // ---- epilogue: bias + bf16 + LDS transpose -> coalesced 16B stores ----
    float bj[4];
    #pragma unroll
    for (int j = 0; j < 4; j++) bj[j] = bias_cat[col0 + wc * 64 + j * 16 + m];

    unsigned short* stage = (unsigned short*)lds;   // [32][SLD]
    #pragma unroll
    for (int i = 0; i < 4; i++) {
        __syncthreads();                 // LDS free (K-loop or previous slice)
        #pragma unroll
        for (int j = 0; j < 4; j++)
            #pragma unroll
            for (int r = 0; r < 4; r++)
                stage[(wr * 16 + quad * 4 + r) * SLD + wc * 64 + j * 16 + m] =
                    f2b(acc[i][j][r] + bj[j]);
        __syncthreads();
        // 32 rows x 128 cols bf16; 16 consecutive lanes cover 256B of one row
        #pragma unroll
        for (int u = t; u < 512; u += 256) {
            int lr = u >> 4, c8 = u & 15;
            int gr = row0 + ((lr & 16) ? 64 : 0) + i * 16 + (lr & 15);
            if (gr < N) {
                int4 v = *(const int4*)(stage + lr * SLD + c8 * 8);
                *(int4*)(Cb + (size_t)gr * NCAT + col0 + c8 * 8) = v;
            }
        }
    }
}

// ---------------------------------------------------------------------------
// Gather: one wave per dst node; lane holds 4 bf16 cols of the bases row.
__global__ __launch_bounds__(256) void gather_kernel(
        const int* __restrict__ offsets, const int* __restrict__ ebuf,
        const float* __restrict__ dinv, const unsigned short* __restrict__ Cb,
        unsigned short* __restrict__ agg, int N) {
    int wave = (blockIdx.x * blockDim.x + threadIdx.x) >> 6;
    int lane = threadIdx.x & 63;
    if (wave >= N) return;
    int n = wave;
    float di = dinv[n];
    float self = di * di;
    ushort4 u = ((const ushort4*)(Cb + (size_t)n * NCAT))[lane];
    float ax = b2f(u.x) * self, ay = b2f(u.y) * self;
    float az = b2f(u.z) * self, aw = b2f(u.w) * self;
    int e = offsets[n], end = offsets[n + 1];
    for (; e + 1 < end; e += 2) {
        int s0 = ebuf[e], s1 = ebuf[e + 1];
        float n0 = dinv[s0] * di, n1 = dinv[s1] * di;
        ushort4 u0 = ((const ushort4*)(Cb + (size_t)s0 * NCAT))[lane];
        ushort4 u1 = ((const ushort4*)(Cb + (size_t)s1 * NCAT))[lane];
        ax += b2f(u0.x) * n0 + b2f(u1.x) * n1;
        ay += b2f(u0.y) * n0 + b2f(u1.y) * n1;
        az += b2f(u0.z) * n0 + b2f(u1.z) * n1;
        aw += b2f(u0.w) * n0 + b2f(u1.w) * n1;
    }
    if (e < end) {
        int s0 = ebuf[e];
        float n0 = dinv[s0] * di;
        ushort4 u0 = ((const ushort4*)(Cb + (size_t)s0 * NCAT))[lane];
        ax += b2f(u0.x) * n0; ay += b2f(u0.y) * n0;
        az += b2f(u0.z) * n0; aw += b2f(u0.w) * n0;
    }
    ushort4 r;
    r.x = f2b(ax); r.y = f2b(ay); r.z = f2b(az); r.w = f2b(aw);
    ((ushort4*)(agg + (size_t)n * BFH))[lane] = r;
}

// ---------------------------------------------------------------------------
// combine + residual + LayerNorm + ReLU. One block (512 thr) per node.
__global__ __launch_bounds__(512) void combine_kernel(
        const unsigned short* __restrict__ agg, const unsigned short* __restrict__ Cb,
        const float* __restrict__ conv_bias, const float* __restrict__ gamma,
        const float* __restrict__ beta, float* __restrict__ out) {
    int n = blockIdx.x;
    int t = threadIdx.x;
    __shared__ float w[HB];
    __shared__ float rs[8], rs2[8];
    __shared__ float mv[2];
    const unsigned short* crow = Cb + (size_t)n * NCAT;
    if (t < HB) w[t] = b2f(crow[COL_W + t]);
    __syncthreads();

    int h = t >> 6, f = t & 63;
    float conv = 0.0f;
    #pragma unroll
    for (int b = 0; b < NB; b++)
        conv += w[h * NB + b] * b2f(agg[(size_t)n * BFH + b * FH + f]);
    float val = conv + conv_bias[t] + b2f(crow[COL_R + t]);

    float s = val, s2 = val * val;
    #pragma unroll
    for (int o = 32; o > 0; o >>= 1) {
        s  += __shfl_down(s, o, 64);
        s2 += __shfl_down(s2, o, 64);
    }
    int wid = t >> 6, lane = t & 63;
    if (lane == 0) { rs[wid] = s; rs2[wid] = s2; }
    __syncthreads();
    if (t == 0) {
        float S = 0.f, S2 = 0.f;
        #pragma unroll
        for (int i = 0; i < 8; i++) { S += rs[i]; S2 += rs2[i]; }
        float mu = S / (float)ODIM;
        float var = S2 / (float)ODIM - mu * mu;
        mv[0] = mu;
        mv[1] = rsqrtf(var + LN_EPS);
    }
    __syncthreads();
    float o = (val - mv[0]) * mv[1] * gamma[t] + beta[t];
    out[(size_t)n * ODIM + t] = fmaxf(o, 0.0f);
}

// ---------------------------------------------------------------------------
static inline char* ws_alloc(char*& p, size_t bytes) {
    char* r = p;
    p += (bytes + 255) & ~(size_t)255;
    return r;
}

extern "C" void kernel_launch(void* const* d_in, const int* in_sizes, int n_in,
                              void* d_out, int out_size, void* d_ws, size_t ws_size,
                              hipStream_t stream) {
    const float* x         = (const float*)d_in[0];
    const int*   ei        = (const int*)d_in[1];
    const float* W_bases   = (const float*)d_in[2];
    const float* W_comb    = (const float*)d_in[3];
    const float* b_comb    = (const float*)d_in[4];
    const float* conv_bias = (const float*)d_in[5];
    const float* W_res     = (const float*)d_in[6];
    const float* b_res     = (const float*)d_in[7];
    const float* gamma     = (const float*)d_in[8];
    const float* beta      = (const float*)d_in[9];

    int N = in_sizes[0] / KDIM;
    int E = in_sizes[1] / 2;
    const int* src = ei;
    const int* dst = ei + E;

    char* p = (char*)d_ws;
    int*   deg      = (int*)ws_alloc(p, sizeof(int) * (size_t)N);
    int*   offsets  = (int*)ws_alloc(p, sizeof(int) * (size_t)(N + 1));
    int*   woff     = (int*)ws_alloc(p, sizeof(int) * (size_t)N);
    int*   ebuf     = (int*)ws_alloc(p, sizeof(int) * (size_t)E);
    float* dinv     = (float*)ws_alloc(p, sizeof(float) * (size_t)N);
    float* bias_cat = (float*)ws_alloc(p, sizeof(float) * NCAT);
    unsigned short* agg = (unsigned short*)ws_alloc(p, 2ull * N * BFH);
    unsigned short* Cb  = (unsigned short*)ws_alloc(p, 2ull * N * NCAT);
    unsigned short* xb  = (unsigned short*)ws_alloc(p, 2ull * N * KDIM);
    unsigned short* wT  = (unsigned short*)ws_alloc(p, 2ull * NCAT * KDIM);
    float* out = (float*)d_out;

    hipMemsetAsync(deg, 0, sizeof(int) * (size_t)N, stream);

    // conversions + weight staging (one fused kernel)
    long total4 = (long)N * KDIM / 4;
    int nCvtBlocks = (int)((total4 + 255) / 256);
    int nStageBlocks = (NCAT * KDIM + 255) / 256;
    prep_kernel<<<nCvtBlocks + nStageBlocks, 256, 0, stream>>>(
        x, xb, total4, nCvtBlocks, W_bases, W_comb, W_res, b_comb, b_res,
        wT, bias_cat);

    // graph prep
    deg_kernel<<<(E + 255) / 256, 256, 0, stream>>>(dst, deg, E);
    scan_kernel<<<1, SCAN_T, 0, stream>>>(deg, offsets, woff, dinv, N);
    fill_kernel<<<(E + 255) / 256, 256, 0, stream>>>(src, dst, woff, ebuf, E);

    // fused MFMA GEMM -> Cb
    dim3 gg(NCAT / BN, (N + BM - 1) / BM);
    mfma_gemm_kernel<<<gg, 256, 0, stream>>>(xb, wT, bias_cat, Cb, N);

    // aggregate + combine
    gather_kernel<<<(N + 3) / 4, 256, 0, stream>>>(offsets, ebuf, dinv, Cb, agg, N);
    combine_kernel<<<N, 512, 0, stream>>>(agg, Cb, conv_bias, gamma, beta, out);
}

// Round 5
// 513.128 us; speedup vs baseline: 1.2618x; 1.2618x over previous
//
#include <hip/hip_runtime.h>
#include <hip/hip_bf16.h>

// Problem constants: IN=512, OUT=512, H=8, B=4, FH=64
#define KDIM 512
#define ODIM 512
#define NB 4
#define NH 8
#define FH 64
#define BFH 256   // B*FH
#define HB 32     // H*B
#define NCAT 896  // 256 bases | 32 comb | 512 res | 96 pad
#define COL_W 256 // weight col offset in Cb
#define COL_R 288 // residual col offset in Cb
#define LN_EPS 1e-5f
#define SCAN_BLK 1024   // elements per scan block

typedef __attribute__((ext_vector_type(8))) short short8;
typedef __attribute__((ext_vector_type(4))) float floatx4;

__device__ __forceinline__ float b2f(unsigned short u) {
    union { unsigned int i; float f; } v; v.i = ((unsigned int)u) << 16; return v.f;
}
__device__ __forceinline__ unsigned short f2b(float f) {
    __hip_bfloat16 h = __float2bfloat16(f);
    return *(unsigned short*)&h;
}
__device__ __forceinline__ void async16(const void* g, void* l) {
    __builtin_amdgcn_global_load_lds(
        (__attribute__((address_space(1))) unsigned int*)(g),
        (__attribute__((address_space(3))) unsigned int*)(l),
        16, 0, 0);
}

// ---------------------------------------------------------------------------
__global__ void deg_kernel(const int* __restrict__ dst, int* __restrict__ deg, int E) {
    int i = blockIdx.x * blockDim.x + threadIdx.x;
    if (i < E) atomicAdd(&deg[dst[i]], 1);
}

// ---- hierarchical scan: sums -> base scan -> write -----------------------
__global__ __launch_bounds__(256) void scan_sums_kernel(
        const int* __restrict__ deg, int* __restrict__ sums, int N) {
    int t = threadIdx.x;
    int idx = blockIdx.x * SCAN_BLK + t * 4;
    int4 v = {0, 0, 0, 0};
    if (idx + 3 < N) v = *(const int4*)(deg + idx);
    else {
        if (idx < N)     v.x = deg[idx];
        if (idx + 1 < N) v.y = deg[idx + 1];
        if (idx + 2 < N) v.z = deg[idx + 2];
        if (idx + 3 < N) v.w = deg[idx + 3];
    }
    int s = v.x + v.y + v.z + v.w;
    #pragma unroll
    for (int o = 32; o > 0; o >>= 1) s += __shfl_down(s, o, 64);
    __shared__ int ws[4];
    int lane = t & 63, w = t >> 6;
    if (lane == 0) ws[w] = s;
    __syncthreads();
    if (t == 0) sums[blockIdx.x] = ws[0] + ws[1] + ws[2] + ws[3];
}

// single small block: exclusive scan of sums[nb] in place (nb <= 1024)
__global__ __launch_bounds__(1024) void scan_base_kernel(
        int* __restrict__ sums, int nb) {
    __shared__ int sm[1024];
    int t = threadIdx.x;
    int own = (t < nb) ? sums[t] : 0;
    sm[t] = own;
    __syncthreads();
    for (int o = 1; o < 1024; o <<= 1) {
        int u = (t >= o) ? sm[t - o] : 0;
        __syncthreads();
        sm[t] += u;
        __syncthreads();
    }
    if (t < nb) sums[t] = sm[t] - own;   // exclusive base per block
}

__global__ __launch_bounds__(256) void scan_write_kernel(
        const int* __restrict__ deg, const int* __restrict__ bases,
        int* __restrict__ offsets, int* __restrict__ woff,
        float* __restrict__ dinv, int N, int E) {
    int t = threadIdx.x;
    int idx = blockIdx.x * SCAN_BLK + t * 4;
    int4 v = {0, 0, 0, 0};
    if (idx + 3 < N) v = *(const int4*)(deg + idx);
    else {
        if (idx < N)     v.x = deg[idx];
        if (idx + 1 < N) v.y = deg[idx + 1];
        if (idx + 2 < N) v.z = deg[idx + 2];
        if (idx + 3 < N) v.w = deg[idx + 3];
    }
    int s = v.x + v.y + v.z + v.w;
    __shared__ int sm[256];
    sm[t] = s;
    __syncthreads();
    for (int o = 1; o < 256; o <<= 1) {
        int u = (t >= o) ? sm[t - o] : 0;
        __syncthreads();
        sm[t] += u;
        __syncthreads();
    }
    int o0 = sm[t] - s + bases[blockIdx.x];
    int o1 = o0 + v.x, o2 = o1 + v.y, o3 = o2 + v.z;
    if (idx + 3 < N) {
        int4 ov = {o0, o1, o2, o3};
        *(int4*)(offsets + idx) = ov;
        *(int4*)(woff + idx) = ov;
        float4 dv = {rsqrtf((float)v.x + 1.0f), rsqrtf((float)v.y + 1.0f),
                     rsqrtf((float)v.z + 1.0f), rsqrtf((float)v.w + 1.0f)};
        *(float4*)(dinv + idx) = dv;
    } else {
        int oo[4] = {o0, o1, o2, o3};
        int vv[4] = {v.x, v.y, v.z, v.w};
        for (int j = 0; j < 4; j++) {
            if (idx + j < N) {
                offsets[idx + j] = oo[j];
                woff[idx + j] = oo[j];
                dinv[idx + j] = rsqrtf((float)vv[j] + 1.0f);
            }
        }
    }
    if (blockIdx.x == 0 && t == 0) offsets[N] = E;
}

__global__ void fill_kernel(const int* __restrict__ src, const int* __restrict__ dst,
                            int* __restrict__ woff, int* __restrict__ ebuf, int E) {
    int i = blockIdx.x * blockDim.x + threadIdx.x;
    if (i < E) {
        int pos = atomicAdd(&woff[dst[i]], 1);
        ebuf[pos] = src[i];
    }
}

// ---------------------------------------------------------------------------
// Fused: x fp32->bf16  AND  WcatT [896][512] bf16 staging + bias_cat.
__global__ __launch_bounds__(256) void prep_kernel(
        const float* __restrict__ x, unsigned short* __restrict__ xb, long total4,
        int nCvtBlocks,
        const float* __restrict__ Wb, const float* __restrict__ Wc,
        const float* __restrict__ Wr, const float* __restrict__ bcomb,
        const float* __restrict__ bres,
        unsigned short* __restrict__ wT, float* __restrict__ bias_cat) {
    int blk = blockIdx.x;
    if (blk < nCvtBlocks) {
        long i = (long)blk * 256 + threadIdx.x;
        if (i >= total4) return;
        float4 v = ((const float4*)x)[i];
        ushort4 u;
        u.x = f2b(v.x); u.y = f2b(v.y); u.z = f2b(v.z); u.w = f2b(v.w);
        ((ushort4*)xb)[i] = u;
    } else {
        int idx = (blk - nCvtBlocks) * 256 + threadIdx.x;
        if (idx >= NCAT * KDIM) return;
        int c = idx >> 9, k = idx & (KDIM - 1);
        float v;
        if (c < BFH)                   v = Wb[(size_t)k * BFH + c];
        else if (c < COL_R)            v = Wc[(size_t)k * HB + (c - COL_W)];
        else if (c < COL_R + ODIM)     v = Wr[(size_t)k * ODIM + (c - COL_R)];
        else                           v = 0.0f;
        wT[(size_t)c * KDIM + k] = f2b(v);
        if (k == 0) {
            float bv = 0.0f;
            if (c >= COL_W && c < COL_R)             bv = bcomb[c - COL_W];
            else if (c >= COL_R && c < COL_R + ODIM) bv = bres[c - COL_R];
            bias_cat[c] = bv;
        }
    }
}

// ---------------------------------------------------------------------------
// bf16 MFMA GEMM: Cb[N,896] = xb[N,512] @ wT^T + bias_cat, output bf16.
#define BM 128
#define BN 128
#define BK 32
#define SLD 136   // epilogue stage row stride (ushorts)

__global__ __launch_bounds__(256) void mfma_gemm_kernel(
        const unsigned short* __restrict__ xb,   // [N,512] bf16 bits
        const unsigned short* __restrict__ wT,   // [896,512] bf16 bits
        const float* __restrict__ bias_cat,      // [896]
        unsigned short* __restrict__ Cb,         // [N,896] bf16 bits
        int N) {
    __shared__ short lds[8192];                  // As 4096 | Bs 4096 shorts
    short* As = lds;
    short* Bs = lds + 4096;
    int t = threadIdx.x;
    int l = t & 63, w = t >> 6;
    int wr = w >> 1, wc = w & 1;
    int quad = l >> 4, m = l & 15;
    int row0 = blockIdx.y * BM;
    int col0 = blockIdx.x * BN;

    floatx4 acc[4][4];
    floatx4 zero4 = {0.f, 0.f, 0.f, 0.f};
    #pragma unroll
    for (int i = 0; i < 4; i++)
        #pragma unroll
        for (int j = 0; j < 4; j++) acc[i][j] = zero4;

    int ar0 = row0 + (w << 4) + (l >> 2);
    int ar1 = ar0 + 64;
    int brow = col0 + (w << 4) + (l >> 2);
    int kk = (l & 3) * 8;
    const unsigned short* agp0 = xb + (size_t)min(ar0, N - 1) * KDIM + kk;
    const unsigned short* agp1 = xb + (size_t)min(ar1, N - 1) * KDIM + kk;
    const unsigned short* bgp0 = wT + (size_t)brow * KDIM + kk;
    const unsigned short* bgp1 = bgp0 + (size_t)64 * KDIM;
    short* al0 = As + w * 512;
    short* al1 = As + 2048 + w * 512;
    short* bl0 = Bs + w * 512;
    short* bl1 = Bs + 2048 + w * 512;

    for (int k0 = 0; k0 < KDIM; k0 += BK) {
        __syncthreads();
        async16(agp0 + k0, al0);
        async16(agp1 + k0, al1);
        async16(bgp0 + k0, bl0);
        async16(bgp1 + k0, bl1);
        __syncthreads();

        short8 a[4], b[4];
        #pragma unroll
        for (int i = 0; i < 4; i++)
            a[i] = *(const short8*)(As + (wr * 64 + i * 16 + m) * BK + quad * 8);
        #pragma unroll
        for (int j = 0; j < 4; j++)
            b[j] = *(const short8*)(Bs + (wc * 64 + j * 16 + m) * BK + quad * 8);
        #pragma unroll
        for (int i = 0; i < 4; i++)
            #pragma unroll
            for (int j = 0; j < 4; j++)
                acc[i][j] = __builtin_amdgcn_mfma_f32_16x16x32_bf16(
                    a[i], b[j], acc[i][j], 0, 0, 0);
    }

    float bj[4];
    #pragma unroll
    for (int j = 0; j < 4; j++) bj[j] = bias_cat[col0 + wc * 64 + j * 16 + m];

    unsigned short* stage = (unsigned short*)lds;   // [32][SLD]
    #pragma unroll
    for (int i = 0; i < 4; i++) {
        __syncthreads();
        #pragma unroll
        for (int j = 0; j < 4; j++)
            #pragma unroll
            for (int r = 0; r < 4; r++)
                stage[(wr * 16 + quad * 4 + r) * SLD + wc * 64 + j * 16 + m] =
                    f2b(acc[i][j][r] + bj[j]);
        __syncthreads();
        #pragma unroll
        for (int u = t; u < 512; u += 256) {
            int lr = u >> 4, c8 = u & 15;
            int gr = row0 + ((lr & 16) ? 64 : 0) + i * 16 + (lr & 15);
            if (gr < N) {
                int4 v = *(const int4*)(stage + lr * SLD + c8 * 8);
                *(int4*)(Cb + (size_t)gr * NCAT + col0 + c8 * 8) = v;
            }
        }
    }
}

// ---------------------------------------------------------------------------
// Gather: one wave per dst node; lane holds 4 bf16 cols of the bases row.
__global__ __launch_bounds__(256) void gather_kernel(
        const int* __restrict__ offsets, const int* __restrict__ ebuf,
        const float* __restrict__ dinv, const unsigned short* __restrict__ Cb,
        unsigned short* __restrict__ agg, int N) {
    int wave = (blockIdx.x * blockDim.x + threadIdx.x) >> 6;
    int lane = threadIdx.x & 63;
    if (wave >= N) return;
    int n = wave;
    float di = dinv[n];
    float self = di * di;
    ushort4 u = ((const ushort4*)(Cb + (size_t)n * NCAT))[lane];
    float ax = b2f(u.x) * self, ay = b2f(u.y) * self;
    float az = b2f(u.z) * self, aw = b2f(u.w) * self;
    int e = offsets[n], end = offsets[n + 1];
    for (; e + 1 < end; e += 2) {
        int s0 = ebuf[e], s1 = ebuf[e + 1];
        float n0 = dinv[s0] * di, n1 = dinv[s1] * di;
        ushort4 u0 = ((const ushort4*)(Cb + (size_t)s0 * NCAT))[lane];
        ushort4 u1 = ((const ushort4*)(Cb + (size_t)s1 * NCAT))[lane];
        ax += b2f(u0.x) * n0 + b2f(u1.x) * n1;
        ay += b2f(u0.y) * n0 + b2f(u1.y) * n1;
        az += b2f(u0.z) * n0 + b2f(u1.z) * n1;
        aw += b2f(u0.w) * n0 + b2f(u1.w) * n1;
    }
    if (e < end) {
        int s0 = ebuf[e];
        float n0 = dinv[s0] * di;
        ushort4 u0 = ((const ushort4*)(Cb + (size_t)s0 * NCAT))[lane];
        ax += b2f(u0.x) * n0; ay += b2f(u0.y) * n0;
        az += b2f(u0.z) * n0; aw += b2f(u0.w) * n0;
    }
    ushort4 r;
    r.x = f2b(ax); r.y = f2b(ay); r.z = f2b(az); r.w = f2b(aw);
    ((ushort4*)(agg + (size_t)n * BFH))[lane] = r;
}

// ---------------------------------------------------------------------------
// combine + residual + LayerNorm + ReLU. One block (512 thr) per node.
__global__ __launch_bounds__(512) void combine_kernel(
        const unsigned short* __restrict__ agg, const unsigned short* __restrict__ Cb,
        const float* __restrict__ conv_bias, const float* __restrict__ gamma,
        const float* __restrict__ beta, float* __restrict__ out) {
    int n = blockIdx.x;
    int t = threadIdx.x;
    __shared__ float w[HB];
    __shared__ float rs[8], rs2[8];
    __shared__ float mv[2];
    const unsigned short* crow = Cb + (size_t)n * NCAT;
    if (t < HB) w[t] = b2f(crow[COL_W + t]);
    __syncthreads();

    int h = t >> 6, f = t & 63;
    float conv = 0.0f;
    #pragma unroll
    for (int b = 0; b < NB; b++)
        conv += w[h * NB + b] * b2f(agg[(size_t)n * BFH + b * FH + f]);
    float val = conv + conv_bias[t] + b2f(crow[COL_R + t]);

    float s = val, s2 = val * val;
    #pragma unroll
    for (int o = 32; o > 0; o >>= 1) {
        s  += __shfl_down(s, o, 64);
        s2 += __shfl_down(s2, o, 64);
    }
    int wid = t >> 6, lane = t & 63;
    if (lane == 0) { rs[wid] = s; rs2[wid] = s2; }
    __syncthreads();
    if (t == 0) {
        float S = 0.f, S2 = 0.f;
        #pragma unroll
        for (int i = 0; i < 8; i++) { S += rs[i]; S2 += rs2[i]; }
        float mu = S / (float)ODIM;
        float var = S2 / (float)ODIM - mu * mu;
        mv[0] = mu;
        mv[1] = rsqrtf(var + LN_EPS);
    }
    __syncthreads();
    float o = (val - mv[0]) * mv[1] * gamma[t] + beta[t];
    out[(size_t)n * ODIM + t] = fmaxf(o, 0.0f);
}

// ---------------------------------------------------------------------------
static inline char* ws_alloc(char*& p, size_t bytes) {
    char* r = p;
    p += (bytes + 255) & ~(size_t)255;
    return r;
}

extern "C" void kernel_launch(void* const* d_in, const int* in_sizes, int n_in,
                              void* d_out, int out_size, void* d_ws, size_t ws_size,
                              hipStream_t stream) {
    const float* x         = (const float*)d_in[0];
    const int*   ei        = (const int*)d_in[1];
    const float* W_bases   = (const float*)d_in[2];
    const float* W_comb    = (const float*)d_in[3];
    const float* b_comb    = (const float*)d_in[4];
    const float* conv_bias = (const float*)d_in[5];
    const float* W_res     = (const float*)d_in[6];
    const float* b_res     = (const float*)d_in[7];
    const float* gamma     = (const float*)d_in[8];
    const float* beta      = (const float*)d_in[9];

    int N = in_sizes[0] / KDIM;
    int E = in_sizes[1] / 2;
    const int* src = ei;
    const int* dst = ei + E;
    int nScanBlocks = (N + SCAN_BLK - 1) / SCAN_BLK;

    char* p = (char*)d_ws;
    int*   deg      = (int*)ws_alloc(p, sizeof(int) * (size_t)N);
    int*   offsets  = (int*)ws_alloc(p, sizeof(int) * (size_t)(N + 1));
    int*   woff     = (int*)ws_alloc(p, sizeof(int) * (size_t)N);
    int*   ebuf     = (int*)ws_alloc(p, sizeof(int) * (size_t)E);
    int*   sums     = (int*)ws_alloc(p, sizeof(int) * (size_t)nScanBlocks);
    float* dinv     = (float*)ws_alloc(p, sizeof(float) * (size_t)N);
    float* bias_cat = (float*)ws_alloc(p, sizeof(float) * NCAT);
    unsigned short* agg = (unsigned short*)ws_alloc(p, 2ull * N * BFH);
    unsigned short* Cb  = (unsigned short*)ws_alloc(p, 2ull * N * NCAT);
    unsigned short* xb  = (unsigned short*)ws_alloc(p, 2ull * N * KDIM);
    unsigned short* wT  = (unsigned short*)ws_alloc(p, 2ull * NCAT * KDIM);
    float* out = (float*)d_out;

    hipMemsetAsync(deg, 0, sizeof(int) * (size_t)N, stream);

    // conversions + weight staging (one fused kernel)
    long total4 = (long)N * KDIM / 4;
    int nCvtBlocks = (int)((total4 + 255) / 256);
    int nStageBlocks = (NCAT * KDIM + 255) / 256;
    prep_kernel<<<nCvtBlocks + nStageBlocks, 256, 0, stream>>>(
        x, xb, total4, nCvtBlocks, W_bases, W_comb, W_res, b_comb, b_res,
        wT, bias_cat);

    // graph prep: deg -> hierarchical scan -> fill
    deg_kernel<<<(E + 255) / 256, 256, 0, stream>>>(dst, deg, E);
    scan_sums_kernel<<<nScanBlocks, 256, 0, stream>>>(deg, sums, N);
    scan_base_kernel<<<1, 1024, 0, stream>>>(sums, nScanBlocks);
    scan_write_kernel<<<nScanBlocks, 256, 0, stream>>>(deg, sums, offsets, woff,
                                                       dinv, N, E);
    fill_kernel<<<(E + 255) / 256, 256, 0, stream>>>(src, dst, woff, ebuf, E);

    // fused MFMA GEMM -> Cb
    dim3 gg(NCAT / BN, (N + BM - 1) / BM);
    mfma_gemm_kernel<<<gg, 256, 0, stream>>>(xb, wT, bias_cat, Cb, N);

    // aggregate + combine
    gather_kernel<<<(N + 3) / 4, 256, 0, stream>>>(offsets, ebuf, dinv, Cb, agg, N);
    combine_kernel<<<N, 512, 0, stream>>>(agg, Cb, conv_bias, gamma, beta, out);
}